// Round 12
// baseline (340.568 us; speedup 1.0000x reference)
//
#include <hip/hip_runtime.h>

#define D 64
#define CAP 64        // adjacency bucket capacity; Poisson(20) => P(deg>64) ~ 1e-17
#define TSTRIDE 68    // tileT row stride (dwords): 16B-aligned b128 rows, 2-way-max banks
#define CSTRIDE 16    // cursor stride (ints): one cursor per 64B line (round-11 fix)

// ---------------------------------------------------------------------------
// Kernel 0: zero the (padded) cursor array. Kernel, not hipMemsetAsync: stay
// unquestionably graph-capture-safe. 1.6M ints ~ 5 us at BW.
// ---------------------------------------------------------------------------
__global__ __launch_bounds__(256) void zero_cursor_kernel(int* __restrict__ cursor,
                                                          int n)
{
    const int i = blockIdx.x * blockDim.x + threadIdx.x;
    if (i < n) cursor[i] = 0;
}

// ---------------------------------------------------------------------------
// Kernel 1: fused dual GEMM — micro-tiled, ALL operands in LDS, only
// accumulators in registers. (Round-9: confirmed fixed — out of top-5;
// rounds 5/7 showed any per-thread float[64] array gets spilled.)
// ---------------------------------------------------------------------------
__global__ __launch_bounds__(256) void gemm2_kernel(
    const float* __restrict__ verts,
    const float* __restrict__ w0, const float* __restrict__ b0,
    const float* __restrict__ w1, const float* __restrict__ b1,
    float* __restrict__ out, float* __restrict__ vw1, int nrows)
{
    __shared__ float tileT[D][TSTRIDE];   // [k][row], 17.4 KB
    __shared__ float w0s[D][D];           // [k][col], 16 KB
    __shared__ float w1s[D][D];           // [k][col], 16 KB
    __shared__ float b0s[D], b1s[D];

    const int tid  = threadIdx.x;
    const int base = blockIdx.x * 64;
    int rows = nrows - base; if (rows > 64) rows = 64;

    // ---- stage weights + bias (linear float4 copy, coalesced) ----
    {
        const float4* s0 = (const float4*)w0;
        const float4* s1 = (const float4*)w1;
        float4* d0 = (float4*)&w0s[0][0];
        float4* d1 = (float4*)&w1s[0][0];
        for (int j = tid; j < (D * D) / 4; j += 256) { d0[j] = s0[j]; d1[j] = s1[j]; }
        if (tid < D) { b0s[tid] = b0[tid]; b1s[tid] = b1[tid]; }
    }

    // ---- stage verts tile transposed ----
    {
        const int row = tid >> 2;
        const int q   = tid & 3;
        if (row < rows) {
            const float4* src = (const float4*)(verts + (size_t)(base + row) * D);
#pragma unroll
            for (int it = 0; it < 4; ++it) {
                const float4 f = src[q * 4 + it];
                const int k = q * 16 + it * 4;
                tileT[k + 0][row] = f.x;
                tileT[k + 1][row] = f.y;
                tileT[k + 2][row] = f.z;
                tileT[k + 3][row] = f.w;
            }
        }
    }
    __syncthreads();

    // ---- compute: 4x4 micro-tile per lane, both matrices ----
    const int lane = tid & 63;
    const int wid  = tid >> 6;
    const int r0   = (lane & 15) * 4;            // rows 0..60
    const int c0   = wid * 16 + (lane >> 4) * 4; // cols 0..60

    const float4 bias0 = *(const float4*)&b0s[c0];
    const float4 bias1 = *(const float4*)&b1s[c0];
    float4 acc0[4], acc1[4];
#pragma unroll
    for (int i = 0; i < 4; ++i) { acc0[i] = bias0; acc1[i] = bias1; }

#define FMA4(ACC, S, B) \
    ACC.x = fmaf(S, B.x, ACC.x); ACC.y = fmaf(S, B.y, ACC.y); \
    ACC.z = fmaf(S, B.z, ACC.z); ACC.w = fmaf(S, B.w, ACC.w)

#pragma unroll 4
    for (int k = 0; k < D; ++k) {
        const float4 a   = *(const float4*)&tileT[k][r0];
        const float4 bv0 = *(const float4*)&w0s[k][c0];
        const float4 bv1 = *(const float4*)&w1s[k][c0];
        FMA4(acc0[0], a.x, bv0); FMA4(acc0[1], a.y, bv0);
        FMA4(acc0[2], a.z, bv0); FMA4(acc0[3], a.w, bv0);
        FMA4(acc1[0], a.x, bv1); FMA4(acc1[1], a.y, bv1);
        FMA4(acc1[2], a.z, bv1); FMA4(acc1[3], a.w, bv1);
    }
#undef FMA4

#pragma unroll
    for (int i = 0; i < 4; ++i) {
        const int row = base + r0 + i;
        if (row < nrows) {
            *(float4*)&out[(size_t)row * D + c0] = acc0[i];
            *(float4*)&vw1[(size_t)row * D + c0] = acc1[i];
        }
    }
}

// ---------------------------------------------------------------------------
// Kernel 2: bucket neighbor IDs. Round-11 post-mortem: ILP restructure was a
// null (172 us, WRITE unchanged, 2x outstanding atomics -> no change) =>
// latency model refuted; wall is line-level contention: 16 cursors/64B line
// x ~20 atomics each = ~320 cross-XCD visits per line, serialized (~160 us).
// Fix: CSTRIDE=16 pads cursors to ONE PER LINE (per-line RMWs 320 -> 20).
// Edge-pair ILP shape kept from round 9 (harmless, proven correct).
// ---------------------------------------------------------------------------
__global__ __launch_bounds__(256) void build_adj_kernel(
    const int* __restrict__ edges, int* __restrict__ cursor,
    int* __restrict__ adj, const float* __restrict__ vw1,
    float* __restrict__ out, int nedges)
{
    const int i  = blockIdx.x * blockDim.x + threadIdx.x;  // edge-pair index
    const int e0 = i * 2;
    if (e0 >= nedges) return;
    const bool two = (e0 + 1 < nedges);

    int s0, t0, s1 = 0, t1 = 0;
    if (two) {
        const int4 p = *(const int4*)(edges + (size_t)e0 * 2);  // 2 edges, 16B
        s0 = p.x; t0 = p.y; s1 = p.z; t1 = p.w;
    } else {
        s0 = edges[(size_t)e0 * 2 + 0];
        t0 = edges[(size_t)e0 * 2 + 1];
    }

    // All cursor atomics in flight before any consumer (one cursor per line).
    const int ps0 = atomicAdd(&cursor[(size_t)s0 * CSTRIDE], 1);
    const int pt0 = atomicAdd(&cursor[(size_t)t0 * CSTRIDE], 1);
    int ps1 = 0, pt1 = 0;
    if (two) {
        ps1 = atomicAdd(&cursor[(size_t)s1 * CSTRIDE], 1);
        pt1 = atomicAdd(&cursor[(size_t)t1 * CSTRIDE], 1);
    }

    // Stores drain as results return.
    if (ps0 < CAP) adj[(size_t)s0 * CAP + ps0] = t0;
    if (pt0 < CAP) adj[(size_t)t0 * CAP + pt0] = s0;
    if (two) {
        if (ps1 < CAP) adj[(size_t)s1 * CAP + ps1] = t1;
        if (pt1 < CAP) adj[(size_t)t1 * CAP + pt1] = s1;
    }

    // Rare overflow fallback (correct for any input; ~never taken here).
    if (ps0 >= CAP) { const float* src = vw1 + (size_t)t0 * D; float* dst = out + (size_t)s0 * D;
        for (int k = 0; k < D; ++k) unsafeAtomicAdd(dst + k, src[k]); }
    if (pt0 >= CAP) { const float* src = vw1 + (size_t)s0 * D; float* dst = out + (size_t)t0 * D;
        for (int k = 0; k < D; ++k) unsafeAtomicAdd(dst + k, src[k]); }
    if (two && ps1 >= CAP) { const float* src = vw1 + (size_t)t1 * D; float* dst = out + (size_t)s1 * D;
        for (int k = 0; k < D; ++k) unsafeAtomicAdd(dst + k, src[k]); }
    if (two && pt1 >= CAP) { const float* src = vw1 + (size_t)s1 * D; float* dst = out + (size_t)t1 * D;
        for (int k = 0; k < D; ++k) unsafeAtomicAdd(dst + k, src[k]); }
}

// ---------------------------------------------------------------------------
// Kernel 3: pull-gather. One 16-lane group per vertex; lane owns 4 columns.
// ---------------------------------------------------------------------------
__global__ __launch_bounds__(256) void gather_kernel(
    const int* __restrict__ cursor, const int* __restrict__ adj,
    const float* __restrict__ vw1, float* __restrict__ out, int nverts)
{
    const int gid = blockIdx.x * blockDim.x + threadIdx.x;
    const int v   = gid >> 4;
    if (v >= nverts) return;
    const int sub = (gid & 15) << 2;

    int deg = cursor[(size_t)v * CSTRIDE]; if (deg > CAP) deg = CAP;
    const int* nb = adj + (size_t)v * CAP;

    float4 acc = make_float4(0.f, 0.f, 0.f, 0.f);
    int i = 0;
    for (; i + 4 <= deg; i += 4) {
        const int4 u4 = *(const int4*)(nb + i);   // 16B-aligned (CAP%4==0)
        const float4 f0 = *(const float4*)(vw1 + (size_t)u4.x * D + sub);
        const float4 f1 = *(const float4*)(vw1 + (size_t)u4.y * D + sub);
        const float4 f2 = *(const float4*)(vw1 + (size_t)u4.z * D + sub);
        const float4 f3 = *(const float4*)(vw1 + (size_t)u4.w * D + sub);
        acc.x += f0.x + f1.x + f2.x + f3.x;
        acc.y += f0.y + f1.y + f2.y + f3.y;
        acc.z += f0.z + f1.z + f2.z + f3.z;
        acc.w += f0.w + f1.w + f2.w + f3.w;
    }
    for (; i < deg; ++i) {
        const int u = nb[i];
        const float4 f = *(const float4*)(vw1 + (size_t)u * D + sub);
        acc.x += f.x; acc.y += f.y; acc.z += f.z; acc.w += f.w;
    }

    float4* po = (float4*)(out + (size_t)v * D + sub);
    float4 o = *po;
    o.x += acc.x; o.y += acc.y; o.z += acc.z; o.w += acc.w;
    *po = o;
}

// ---------------------------------------------------------------------------
// Fallback (ws too small): round-2's proven atomic scatter.
// ---------------------------------------------------------------------------
__global__ __launch_bounds__(256) void scatter_add_kernel(
    const int* __restrict__ edges, const float* __restrict__ vw1,
    float* __restrict__ out, int nedges)
{
    const int gid = blockIdx.x * blockDim.x + threadIdx.x;
    const int e   = gid >> 4;
    if (e >= nedges) return;
    const int sub = (gid & 15) << 2;
    const int s = edges[(size_t)e * 2 + 0];
    const int t = edges[(size_t)e * 2 + 1];
    const float4 fd = *(const float4*)(vw1 + (size_t)t * D + sub);
    const float4 fs = *(const float4*)(vw1 + (size_t)s * D + sub);
    float* po = out + (size_t)s * D + sub;
    unsafeAtomicAdd(po + 0, fd.x); unsafeAtomicAdd(po + 1, fd.y);
    unsafeAtomicAdd(po + 2, fd.z); unsafeAtomicAdd(po + 3, fd.w);
    float* pt = out + (size_t)t * D + sub;
    unsafeAtomicAdd(pt + 0, fs.x); unsafeAtomicAdd(pt + 1, fs.y);
    unsafeAtomicAdd(pt + 2, fs.z); unsafeAtomicAdd(pt + 3, fs.w);
}

extern "C" void kernel_launch(void* const* d_in, const int* in_sizes, int n_in,
                              void* d_out, int out_size, void* d_ws, size_t ws_size,
                              hipStream_t stream)
{
    const float* verts = (const float*)d_in[0];
    const int*   edges = (const int*)d_in[1];
    const float* w0k   = (const float*)d_in[2];
    const float* w0b   = (const float*)d_in[3];
    const float* w1k   = (const float*)d_in[4];
    const float* w1b   = (const float*)d_in[5];
    float* out = (float*)d_out;

    const int nrows  = in_sizes[0] / D;
    const int nedges = in_sizes[1] / 2;

    // Workspace layout: vw1 | padded cursor | adj
    const size_t vw1_bytes    = (size_t)nrows * D * sizeof(float);
    const size_t cursor_bytes = (size_t)nrows * CSTRIDE * sizeof(int);  // 6.4 MB
    const size_t adj_bytes    = (size_t)nrows * CAP * sizeof(int);
    float* vw1  = (float*)d_ws;
    int* cursor = (int*)((char*)d_ws + vw1_bytes);
    int* adj    = (int*)((char*)d_ws + vw1_bytes + cursor_bytes);
    const bool csr_ok = ws_size >= vw1_bytes + cursor_bytes + adj_bytes;

    // GEMM: 64 rows per 256-thread block.
    const int gblocks = (nrows + 63) / 64;
    gemm2_kernel<<<gblocks, 256, 0, stream>>>(verts, w0k, w0b, w1k, w1b,
                                              out, vw1, nrows);

    if (csr_ok) {
        const int ncur    = nrows * CSTRIDE;
        const int zblocks = (ncur + 255) / 256;
        zero_cursor_kernel<<<zblocks, 256, 0, stream>>>(cursor, ncur);
        const int npairs  = (nedges + 1) / 2;
        const int bblocks = (npairs + 255) / 256;
        build_adj_kernel<<<bblocks, 256, 0, stream>>>(edges, cursor, adj,
                                                      vw1, out, nedges);
        const long long ngroups = (long long)nrows * 16;
        const int vblocks = (int)((ngroups + 255) / 256);
        gather_kernel<<<vblocks, 256, 0, stream>>>(cursor, adj, vw1, out, nrows);
    } else {
        const long long ngroups = (long long)nedges * 16;
        const int blocks = (int)((ngroups + 255) / 256);
        scatter_add_kernel<<<blocks, 256, 0, stream>>>(edges, vw1, out, nedges);
    }
}

// Round 14
// 286.416 us; speedup vs baseline: 1.1891x; 1.1891x over previous
//
#include <hip/hip_runtime.h>

#define D 64
#define CAP 64      // adjacency bucket capacity; Poisson(20) => P(deg>64) ~ 1e-17
#define TSTRIDE 68  // tileT row stride (dwords): 16B-aligned b128 rows, 2-way-max banks

// ---------------------------------------------------------------------------
// Kernel 0: zero cursor array + overflow counter (kernel, graph-capture-safe).
// ---------------------------------------------------------------------------
__global__ __launch_bounds__(256) void zero_cursor_kernel(int* __restrict__ cursor,
                                                          int n, int* __restrict__ ovf_cnt)
{
    const int i = blockIdx.x * blockDim.x + threadIdx.x;
    if (i < n) cursor[i] = 0;
    if (i == 0) *ovf_cnt = 0;
}

// ---------------------------------------------------------------------------
// Kernel 1 (FUSED): grid-partitioned gemm + build_adj.
// Round-12 model: build_adj sits at a device-global ~20-25 G scattered
// line-transaction/s wall (ILP null r11, cursor-padding null r12; round-2
// scatter at 19 G lines/s corroborates). It can't go faster without a sort;
// but it leaves VALU idle (0.4%) — so overlap the VALU-bound GEMM under it.
// Bresenham role interleave => every CU hosts both block kinds.
//   build blocks: 2 edges/thread, 4 returning cursor atomics + 4 adj stores;
//                 overflow (deg>CAP) defers (s,t) to ovf_list (vw1 not ready).
//   gemm blocks:  round-9 proven micro-tiled dual GEMM, all operands in LDS.
// ---------------------------------------------------------------------------
__global__ __launch_bounds__(256) void fused_gemm_build_kernel(
    const float* __restrict__ verts,
    const float* __restrict__ w0, const float* __restrict__ b0,
    const float* __restrict__ w1, const float* __restrict__ b1,
    float* __restrict__ out, float* __restrict__ vw1, int nrows,
    const int* __restrict__ edges, int* __restrict__ cursor,
    int* __restrict__ adj, int nedges,
    int* __restrict__ ovf_cnt, int2* __restrict__ ovf_list, int ovf_cap,
    int nb /* build blocks */, int ntot /* total blocks */)
{
    __shared__ float tileT[D][TSTRIDE];   // [k][row], 17.4 KB
    __shared__ float w0s[D][D];           // 16 KB
    __shared__ float w1s[D][D];           // 16 KB
    __shared__ float b0s[D], b1s[D];

    const int tid = threadIdx.x;

    // Bresenham role split: block i is a build block iff floor((i+1)nb/T) >
    // floor(i*nb/T); its build id is floor(i*nb/T); else gemm id = i - that.
    const long long ib  = ((long long)blockIdx.x * nb) / ntot;
    const long long ib1 = (((long long)blockIdx.x + 1) * nb) / ntot;

    if (ib1 > ib) {
        // ================= build part =================
        const int i  = (int)ib * 256 + tid;       // edge-pair index
        const int e0 = i * 2;
        if (e0 >= nedges) return;
        const bool two = (e0 + 1 < nedges);

        int s0, t0, s1 = 0, t1 = 0;
        if (two) {
            const int4 p = *(const int4*)(edges + (size_t)e0 * 2);
            s0 = p.x; t0 = p.y; s1 = p.z; t1 = p.w;
        } else {
            s0 = edges[(size_t)e0 * 2 + 0];
            t0 = edges[(size_t)e0 * 2 + 1];
        }

        const int ps0 = atomicAdd(&cursor[s0], 1);
        const int pt0 = atomicAdd(&cursor[t0], 1);
        int ps1 = 0, pt1 = 0;
        if (two) {
            ps1 = atomicAdd(&cursor[s1], 1);
            pt1 = atomicAdd(&cursor[t1], 1);
        }

        if (ps0 < CAP) adj[(size_t)s0 * CAP + ps0] = t0;
        else { const int x = atomicAdd(ovf_cnt, 1); if (x < ovf_cap) ovf_list[x] = make_int2(s0, t0); }
        if (pt0 < CAP) adj[(size_t)t0 * CAP + pt0] = s0;
        else { const int x = atomicAdd(ovf_cnt, 1); if (x < ovf_cap) ovf_list[x] = make_int2(t0, s0); }
        if (two) {
            if (ps1 < CAP) adj[(size_t)s1 * CAP + ps1] = t1;
            else { const int x = atomicAdd(ovf_cnt, 1); if (x < ovf_cap) ovf_list[x] = make_int2(s1, t1); }
            if (pt1 < CAP) adj[(size_t)t1 * CAP + pt1] = s1;
            else { const int x = atomicAdd(ovf_cnt, 1); if (x < ovf_cap) ovf_list[x] = make_int2(t1, s1); }
        }
        return;
    }

    // ================= gemm part =================
    const int gid  = blockIdx.x - (int)ib;
    const int base = gid * 64;
    if (base >= nrows) return;
    int rows = nrows - base; if (rows > 64) rows = 64;

    {
        const float4* sw0 = (const float4*)w0;
        const float4* sw1 = (const float4*)w1;
        float4* d0 = (float4*)&w0s[0][0];
        float4* d1 = (float4*)&w1s[0][0];
        for (int j = tid; j < (D * D) / 4; j += 256) { d0[j] = sw0[j]; d1[j] = sw1[j]; }
        if (tid < D) { b0s[tid] = b0[tid]; b1s[tid] = b1[tid]; }
    }
    {
        const int row = tid >> 2;
        const int q   = tid & 3;
        if (row < rows) {
            const float4* src = (const float4*)(verts + (size_t)(base + row) * D);
#pragma unroll
            for (int it = 0; it < 4; ++it) {
                const float4 f = src[q * 4 + it];
                const int k = q * 16 + it * 4;
                tileT[k + 0][row] = f.x;
                tileT[k + 1][row] = f.y;
                tileT[k + 2][row] = f.z;
                tileT[k + 3][row] = f.w;
            }
        }
    }
    __syncthreads();

    const int lane = tid & 63;
    const int wid  = tid >> 6;
    const int r0   = (lane & 15) * 4;
    const int c0   = wid * 16 + (lane >> 4) * 4;

    const float4 bias0 = *(const float4*)&b0s[c0];
    const float4 bias1 = *(const float4*)&b1s[c0];
    float4 acc0[4], acc1[4];
#pragma unroll
    for (int i = 0; i < 4; ++i) { acc0[i] = bias0; acc1[i] = bias1; }

#define FMA4(ACC, S, B) \
    ACC.x = fmaf(S, B.x, ACC.x); ACC.y = fmaf(S, B.y, ACC.y); \
    ACC.z = fmaf(S, B.z, ACC.z); ACC.w = fmaf(S, B.w, ACC.w)

#pragma unroll 4
    for (int k = 0; k < D; ++k) {
        const float4 a   = *(const float4*)&tileT[k][r0];
        const float4 bv0 = *(const float4*)&w0s[k][c0];
        const float4 bv1 = *(const float4*)&w1s[k][c0];
        FMA4(acc0[0], a.x, bv0); FMA4(acc0[1], a.y, bv0);
        FMA4(acc0[2], a.z, bv0); FMA4(acc0[3], a.w, bv0);
        FMA4(acc1[0], a.x, bv1); FMA4(acc1[1], a.y, bv1);
        FMA4(acc1[2], a.z, bv1); FMA4(acc1[3], a.w, bv1);
    }
#undef FMA4

#pragma unroll
    for (int i = 0; i < 4; ++i) {
        const int row = base + r0 + i;
        if (row < nrows) {
            *(float4*)&out[(size_t)row * D + c0] = acc0[i];
            *(float4*)&vw1[(size_t)row * D + c0] = acc1[i];
        }
    }
}

// ---------------------------------------------------------------------------
// Kernel 2: pull-gather. One 16-lane group per vertex; lane owns 4 columns.
// ---------------------------------------------------------------------------
__global__ __launch_bounds__(256) void gather_kernel(
    const int* __restrict__ cursor, const int* __restrict__ adj,
    const float* __restrict__ vw1, float* __restrict__ out, int nverts)
{
    const int gid = blockIdx.x * blockDim.x + threadIdx.x;
    const int v   = gid >> 4;
    if (v >= nverts) return;
    const int sub = (gid & 15) << 2;

    int deg = cursor[v]; if (deg > CAP) deg = CAP;
    const int* nb = adj + (size_t)v * CAP;

    float4 acc = make_float4(0.f, 0.f, 0.f, 0.f);
    int i = 0;
    for (; i + 4 <= deg; i += 4) {
        const int4 u4 = *(const int4*)(nb + i);
        const float4 f0 = *(const float4*)(vw1 + (size_t)u4.x * D + sub);
        const float4 f1 = *(const float4*)(vw1 + (size_t)u4.y * D + sub);
        const float4 f2 = *(const float4*)(vw1 + (size_t)u4.z * D + sub);
        const float4 f3 = *(const float4*)(vw1 + (size_t)u4.w * D + sub);
        acc.x += f0.x + f1.x + f2.x + f3.x;
        acc.y += f0.y + f1.y + f2.y + f3.y;
        acc.z += f0.z + f1.z + f2.z + f3.z;
        acc.w += f0.w + f1.w + f2.w + f3.w;
    }
    for (; i < deg; ++i) {
        const int u = nb[i];
        const float4 f = *(const float4*)(vw1 + (size_t)u * D + sub);
        acc.x += f.x; acc.y += f.y; acc.z += f.z; acc.w += f.w;
    }

    float4* po = (float4*)(out + (size_t)v * D + sub);
    float4 o = *po;
    o.x += acc.x; o.y += acc.y; o.z += acc.z; o.w += acc.w;
    *po = o;
}

// ---------------------------------------------------------------------------
// Kernel 3: apply deferred overflow entries (out[a] += vw1[b]); runs after
// gather, atomics safe on top of gather's plain RMW. Normally zero entries.
// ---------------------------------------------------------------------------
__global__ __launch_bounds__(256) void ovf_apply_kernel(
    const int* __restrict__ ovf_cnt, const int2* __restrict__ ovf_list,
    int ovf_cap, const float* __restrict__ vw1, float* __restrict__ out)
{
    int n = *ovf_cnt; if (n > ovf_cap) n = ovf_cap;
    const int gid = blockIdx.x * blockDim.x + threadIdx.x;
    const int sub = (gid & 15) << 2;
    const int stride = (gridDim.x * blockDim.x) >> 4;
    for (int idx = gid >> 4; idx < n; idx += stride) {
        const int2 p = ovf_list[idx];
        const float4 f = *(const float4*)(vw1 + (size_t)p.y * D + sub);
        float* dst = out + (size_t)p.x * D + sub;
        unsafeAtomicAdd(dst + 0, f.x); unsafeAtomicAdd(dst + 1, f.y);
        unsafeAtomicAdd(dst + 2, f.z); unsafeAtomicAdd(dst + 3, f.w);
    }
}

// ---------------------------------------------------------------------------
// Fallback (ws too small): round-2's proven atomic scatter.
// ---------------------------------------------------------------------------
__global__ __launch_bounds__(256) void scatter_add_kernel(
    const int* __restrict__ edges, const float* __restrict__ vw1,
    float* __restrict__ out, int nedges)
{
    const int gid = blockIdx.x * blockDim.x + threadIdx.x;
    const int e   = gid >> 4;
    if (e >= nedges) return;
    const int sub = (gid & 15) << 2;
    const int s = edges[(size_t)e * 2 + 0];
    const int t = edges[(size_t)e * 2 + 1];
    const float4 fd = *(const float4*)(vw1 + (size_t)t * D + sub);
    const float4 fs = *(const float4*)(vw1 + (size_t)s * D + sub);
    float* po = out + (size_t)s * D + sub;
    unsafeAtomicAdd(po + 0, fd.x); unsafeAtomicAdd(po + 1, fd.y);
    unsafeAtomicAdd(po + 2, fd.z); unsafeAtomicAdd(po + 3, fd.w);
    float* pt = out + (size_t)t * D + sub;
    unsafeAtomicAdd(pt + 0, fs.x); unsafeAtomicAdd(pt + 1, fs.y);
    unsafeAtomicAdd(pt + 2, fs.z); unsafeAtomicAdd(pt + 3, fs.w);
}

extern "C" void kernel_launch(void* const* d_in, const int* in_sizes, int n_in,
                              void* d_out, int out_size, void* d_ws, size_t ws_size,
                              hipStream_t stream)
{
    const float* verts = (const float*)d_in[0];
    const int*   edges = (const int*)d_in[1];
    const float* w0k   = (const float*)d_in[2];
    const float* w0b   = (const float*)d_in[3];
    const float* w1k   = (const float*)d_in[4];
    const float* w1b   = (const float*)d_in[5];
    float* out = (float*)d_out;

    const int nrows  = in_sizes[0] / D;
    const int nedges = in_sizes[1] / 2;

    // Workspace: vw1 | adj | cursor | ovf_cnt(64B) | ovf_list(rest)
    const size_t vw1_bytes    = (size_t)nrows * D * sizeof(float);
    const size_t adj_bytes    = (size_t)nrows * CAP * sizeof(int);
    const size_t cursor_bytes = ((size_t)nrows * sizeof(int) + 63) & ~(size_t)63;
    float* vw1  = (float*)d_ws;
    int*   adj  = (int*)((char*)d_ws + vw1_bytes);
    int* cursor = (int*)((char*)d_ws + vw1_bytes + adj_bytes);
    int* ovf_cnt = (int*)((char*)d_ws + vw1_bytes + adj_bytes + cursor_bytes);
    int2* ovf_list = (int2*)((char*)ovf_cnt + 64);
    const size_t fixed_bytes = vw1_bytes + adj_bytes + cursor_bytes + 64;
    long long ovf_cap = 0;
    if (ws_size > fixed_bytes) ovf_cap = (long long)((ws_size - fixed_bytes) / sizeof(int2));
    if (ovf_cap > 2LL * nedges) ovf_cap = 2LL * nedges;
    const bool csr_ok = (ws_size >= fixed_bytes) && (ovf_cap >= 4096);

    const int ngemm = (nrows + 63) / 64;

    if (csr_ok) {
        const int zblocks = (nrows + 255) / 256;
        zero_cursor_kernel<<<zblocks, 256, 0, stream>>>(cursor, nrows, ovf_cnt);

        const int npairs = (nedges + 1) / 2;
        const int nb     = (npairs + 255) / 256;
        const int ntot   = nb + ngemm;
        fused_gemm_build_kernel<<<ntot, 256, 0, stream>>>(
            verts, w0k, w0b, w1k, w1b, out, vw1, nrows,
            edges, cursor, adj, nedges,
            ovf_cnt, ovf_list, (int)ovf_cap, nb, ntot);

        const long long ngroups = (long long)nrows * 16;
        const int vblocks = (int)((ngroups + 255) / 256);
        gather_kernel<<<vblocks, 256, 0, stream>>>(cursor, adj, vw1, out, nrows);

        ovf_apply_kernel<<<64, 256, 0, stream>>>(ovf_cnt, ovf_list,
                                                 (int)ovf_cap, vw1, out);
    } else {
        // gemm-only pass through the fused kernel (nb = 0 -> all gemm blocks)
        fused_gemm_build_kernel<<<ngemm, 256, 0, stream>>>(
            verts, w0k, w0b, w1k, w1b, out, vw1, nrows,
            edges, (int*)d_ws, (int*)d_ws, 0,
            (int*)d_ws, (int2*)d_ws, 0, 0, ngemm);
        const long long ngroups = (long long)nedges * 16;
        const int blocks = (int)((ngroups + 255) / 256);
        scatter_add_kernel<<<blocks, 256, 0, stream>>>(edges, vw1, out, nedges);
    }
}

// Round 15
// 267.922 us; speedup vs baseline: 1.2711x; 1.0690x over previous
//
#include <hip/hip_runtime.h>

#define D 64
#define CAP 64      // adjacency bucket capacity; Poisson(20) => P(deg>64) ~ 1e-17
#define TSTRIDE 68  // tileT row stride (dwords): 16B-aligned b128 rows, 2-way-max banks

// bf16 helpers (manual: exact bit semantics, no header dependency surprises)
static __device__ __forceinline__ unsigned short f2bf(float f) {
    const unsigned int u = __float_as_uint(f);
    return (unsigned short)((u + 0x7FFFu + ((u >> 16) & 1u)) >> 16);   // RNE
}
static __device__ __forceinline__ float bf2f(unsigned short h) {
    return __uint_as_float((unsigned int)h << 16);
}

// ---------------------------------------------------------------------------
// Kernel 0: zero cursor array + overflow counter (kernel, graph-capture-safe).
// ---------------------------------------------------------------------------
__global__ __launch_bounds__(256) void zero_cursor_kernel(int* __restrict__ cursor,
                                                          int n, int* __restrict__ ovf_cnt)
{
    const int i = blockIdx.x * blockDim.x + threadIdx.x;
    if (i < n) cursor[i] = 0;
    if (i == 0) *ovf_cnt = 0;
}

// ---------------------------------------------------------------------------
// Kernel 1 (FUSED): grid-partitioned gemm + build_adj. (Round-14: 153 us,
// VALUBusy 8.4%, fusion confirmed — build wall is device-global transaction
// throughput, gemm rides under it.) Round-15 change: vw1 stored as BF16
// (halves gather read traffic + vw1 write traffic; gather is the remaining
// ~115 us inferred cost at ~4.4 TB/s effective).
// ---------------------------------------------------------------------------
__global__ __launch_bounds__(256) void fused_gemm_build_kernel(
    const float* __restrict__ verts,
    const float* __restrict__ w0, const float* __restrict__ b0,
    const float* __restrict__ w1, const float* __restrict__ b1,
    float* __restrict__ out, unsigned short* __restrict__ vw1b, int nrows,
    const int* __restrict__ edges, int* __restrict__ cursor,
    int* __restrict__ adj, int nedges,
    int* __restrict__ ovf_cnt, int2* __restrict__ ovf_list, int ovf_cap,
    int nb /* build blocks */, int ntot /* total blocks */)
{
    __shared__ float tileT[D][TSTRIDE];   // [k][row], 17.4 KB
    __shared__ float w0s[D][D];           // 16 KB
    __shared__ float w1s[D][D];           // 16 KB
    __shared__ float b0s[D], b1s[D];

    const int tid = threadIdx.x;

    const long long ib  = ((long long)blockIdx.x * nb) / ntot;
    const long long ib1 = (((long long)blockIdx.x + 1) * nb) / ntot;

    if (ib1 > ib) {
        // ================= build part (unchanged from round 14) ===========
        const int i  = (int)ib * 256 + tid;
        const int e0 = i * 2;
        if (e0 >= nedges) return;
        const bool two = (e0 + 1 < nedges);

        int s0, t0, s1 = 0, t1 = 0;
        if (two) {
            const int4 p = *(const int4*)(edges + (size_t)e0 * 2);
            s0 = p.x; t0 = p.y; s1 = p.z; t1 = p.w;
        } else {
            s0 = edges[(size_t)e0 * 2 + 0];
            t0 = edges[(size_t)e0 * 2 + 1];
        }

        const int ps0 = atomicAdd(&cursor[s0], 1);
        const int pt0 = atomicAdd(&cursor[t0], 1);
        int ps1 = 0, pt1 = 0;
        if (two) {
            ps1 = atomicAdd(&cursor[s1], 1);
            pt1 = atomicAdd(&cursor[t1], 1);
        }

        if (ps0 < CAP) adj[(size_t)s0 * CAP + ps0] = t0;
        else { const int x = atomicAdd(ovf_cnt, 1); if (x < ovf_cap) ovf_list[x] = make_int2(s0, t0); }
        if (pt0 < CAP) adj[(size_t)t0 * CAP + pt0] = s0;
        else { const int x = atomicAdd(ovf_cnt, 1); if (x < ovf_cap) ovf_list[x] = make_int2(t0, s0); }
        if (two) {
            if (ps1 < CAP) adj[(size_t)s1 * CAP + ps1] = t1;
            else { const int x = atomicAdd(ovf_cnt, 1); if (x < ovf_cap) ovf_list[x] = make_int2(s1, t1); }
            if (pt1 < CAP) adj[(size_t)t1 * CAP + pt1] = s1;
            else { const int x = atomicAdd(ovf_cnt, 1); if (x < ovf_cap) ovf_list[x] = make_int2(t1, s1); }
        }
        return;
    }

    // ================= gemm part =================
    const int gid  = blockIdx.x - (int)ib;
    const int base = gid * 64;
    if (base >= nrows) return;
    int rows = nrows - base; if (rows > 64) rows = 64;

    {
        const float4* sw0 = (const float4*)w0;
        const float4* sw1 = (const float4*)w1;
        float4* d0 = (float4*)&w0s[0][0];
        float4* d1 = (float4*)&w1s[0][0];
        for (int j = tid; j < (D * D) / 4; j += 256) { d0[j] = sw0[j]; d1[j] = sw1[j]; }
        if (tid < D) { b0s[tid] = b0[tid]; b1s[tid] = b1[tid]; }
    }
    {
        const int row = tid >> 2;
        const int q   = tid & 3;
        if (row < rows) {
            const float4* src = (const float4*)(verts + (size_t)(base + row) * D);
#pragma unroll
            for (int it = 0; it < 4; ++it) {
                const float4 f = src[q * 4 + it];
                const int k = q * 16 + it * 4;
                tileT[k + 0][row] = f.x;
                tileT[k + 1][row] = f.y;
                tileT[k + 2][row] = f.z;
                tileT[k + 3][row] = f.w;
            }
        }
    }
    __syncthreads();

    const int lane = tid & 63;
    const int wid  = tid >> 6;
    const int r0   = (lane & 15) * 4;
    const int c0   = wid * 16 + (lane >> 4) * 4;

    const float4 bias0 = *(const float4*)&b0s[c0];
    const float4 bias1 = *(const float4*)&b1s[c0];
    float4 acc0[4], acc1[4];
#pragma unroll
    for (int i = 0; i < 4; ++i) { acc0[i] = bias0; acc1[i] = bias1; }

#define FMA4(ACC, S, B) \
    ACC.x = fmaf(S, B.x, ACC.x); ACC.y = fmaf(S, B.y, ACC.y); \
    ACC.z = fmaf(S, B.z, ACC.z); ACC.w = fmaf(S, B.w, ACC.w)

#pragma unroll 4
    for (int k = 0; k < D; ++k) {
        const float4 a   = *(const float4*)&tileT[k][r0];
        const float4 bv0 = *(const float4*)&w0s[k][c0];
        const float4 bv1 = *(const float4*)&w1s[k][c0];
        FMA4(acc0[0], a.x, bv0); FMA4(acc0[1], a.y, bv0);
        FMA4(acc0[2], a.z, bv0); FMA4(acc0[3], a.w, bv0);
        FMA4(acc1[0], a.x, bv1); FMA4(acc1[1], a.y, bv1);
        FMA4(acc1[2], a.z, bv1); FMA4(acc1[3], a.w, bv1);
    }
#undef FMA4

#pragma unroll
    for (int i = 0; i < 4; ++i) {
        const int row = base + r0 + i;
        if (row < nrows) {
            *(float4*)&out[(size_t)row * D + c0] = acc0[i];
            ushort4 h;
            h.x = f2bf(acc1[i].x); h.y = f2bf(acc1[i].y);
            h.z = f2bf(acc1[i].z); h.w = f2bf(acc1[i].w);
            *(ushort4*)&vw1b[(size_t)row * D + c0] = h;   // 8B store
        }
    }
}

// ---------------------------------------------------------------------------
// Kernel 2: pull-gather, bf16 vw1. 16 lanes/vertex, lane owns 4 columns
// (8B ushort4 loads -> 128B/row per group, coalesced); fp32 accumulate.
// ---------------------------------------------------------------------------
__global__ __launch_bounds__(256) void gather_kernel(
    const int* __restrict__ cursor, const int* __restrict__ adj,
    const unsigned short* __restrict__ vw1b, float* __restrict__ out, int nverts)
{
    const int gid = blockIdx.x * blockDim.x + threadIdx.x;
    const int v   = gid >> 4;
    if (v >= nverts) return;
    const int sub = (gid & 15) << 2;

    int deg = cursor[v]; if (deg > CAP) deg = CAP;
    const int* nb = adj + (size_t)v * CAP;

    float4 acc = make_float4(0.f, 0.f, 0.f, 0.f);
    int i = 0;
    for (; i + 4 <= deg; i += 4) {
        const int4 u4 = *(const int4*)(nb + i);
        const ushort4 h0 = *(const ushort4*)(vw1b + (size_t)u4.x * D + sub);
        const ushort4 h1 = *(const ushort4*)(vw1b + (size_t)u4.y * D + sub);
        const ushort4 h2 = *(const ushort4*)(vw1b + (size_t)u4.z * D + sub);
        const ushort4 h3 = *(const ushort4*)(vw1b + (size_t)u4.w * D + sub);
        acc.x += bf2f(h0.x) + bf2f(h1.x) + bf2f(h2.x) + bf2f(h3.x);
        acc.y += bf2f(h0.y) + bf2f(h1.y) + bf2f(h2.y) + bf2f(h3.y);
        acc.z += bf2f(h0.z) + bf2f(h1.z) + bf2f(h2.z) + bf2f(h3.z);
        acc.w += bf2f(h0.w) + bf2f(h1.w) + bf2f(h2.w) + bf2f(h3.w);
    }
    for (; i < deg; ++i) {
        const int u = nb[i];
        const ushort4 h = *(const ushort4*)(vw1b + (size_t)u * D + sub);
        acc.x += bf2f(h.x); acc.y += bf2f(h.y);
        acc.z += bf2f(h.z); acc.w += bf2f(h.w);
    }

    float4* po = (float4*)(out + (size_t)v * D + sub);
    float4 o = *po;
    o.x += acc.x; o.y += acc.y; o.z += acc.z; o.w += acc.w;
    *po = o;
}

// ---------------------------------------------------------------------------
// Kernel 3: apply deferred overflow entries AFTER gather (atomics on top of
// gather's plain RMW would race if merged). Normally zero entries.
// ---------------------------------------------------------------------------
__global__ __launch_bounds__(256) void ovf_apply_kernel(
    const int* __restrict__ ovf_cnt, const int2* __restrict__ ovf_list,
    int ovf_cap, const unsigned short* __restrict__ vw1b, float* __restrict__ out)
{
    int n = *ovf_cnt; if (n > ovf_cap) n = ovf_cap;
    const int gid = blockIdx.x * blockDim.x + threadIdx.x;
    const int sub = (gid & 15) << 2;
    const int stride = (gridDim.x * blockDim.x) >> 4;
    for (int idx = gid >> 4; idx < n; idx += stride) {
        const int2 p = ovf_list[idx];
        const ushort4 h = *(const ushort4*)(vw1b + (size_t)p.y * D + sub);
        float* dst = out + (size_t)p.x * D + sub;
        unsafeAtomicAdd(dst + 0, bf2f(h.x)); unsafeAtomicAdd(dst + 1, bf2f(h.y));
        unsafeAtomicAdd(dst + 2, bf2f(h.z)); unsafeAtomicAdd(dst + 3, bf2f(h.w));
    }
}

// ---------------------------------------------------------------------------
// Fallback (ws too small): atomic scatter, bf16 vw1.
// ---------------------------------------------------------------------------
__global__ __launch_bounds__(256) void scatter_add_kernel(
    const int* __restrict__ edges, const unsigned short* __restrict__ vw1b,
    float* __restrict__ out, int nedges)
{
    const int gid = blockIdx.x * blockDim.x + threadIdx.x;
    const int e   = gid >> 4;
    if (e >= nedges) return;
    const int sub = (gid & 15) << 2;
    const int s = edges[(size_t)e * 2 + 0];
    const int t = edges[(size_t)e * 2 + 1];
    const ushort4 hd = *(const ushort4*)(vw1b + (size_t)t * D + sub);
    const ushort4 hs = *(const ushort4*)(vw1b + (size_t)s * D + sub);
    float* po = out + (size_t)s * D + sub;
    unsafeAtomicAdd(po + 0, bf2f(hd.x)); unsafeAtomicAdd(po + 1, bf2f(hd.y));
    unsafeAtomicAdd(po + 2, bf2f(hd.z)); unsafeAtomicAdd(po + 3, bf2f(hd.w));
    float* pt = out + (size_t)t * D + sub;
    unsafeAtomicAdd(pt + 0, bf2f(hs.x)); unsafeAtomicAdd(pt + 1, bf2f(hs.y));
    unsafeAtomicAdd(pt + 2, bf2f(hs.z)); unsafeAtomicAdd(pt + 3, bf2f(hs.w));
}

extern "C" void kernel_launch(void* const* d_in, const int* in_sizes, int n_in,
                              void* d_out, int out_size, void* d_ws, size_t ws_size,
                              hipStream_t stream)
{
    const float* verts = (const float*)d_in[0];
    const int*   edges = (const int*)d_in[1];
    const float* w0k   = (const float*)d_in[2];
    const float* w0b   = (const float*)d_in[3];
    const float* w1k   = (const float*)d_in[4];
    const float* w1b   = (const float*)d_in[5];
    float* out = (float*)d_out;

    const int nrows  = in_sizes[0] / D;
    const int nedges = in_sizes[1] / 2;

    // Workspace: vw1(bf16) | adj | cursor | ovf_cnt(64B) | ovf_list(rest)
    const size_t vw1_bytes    = (((size_t)nrows * D * sizeof(unsigned short)) + 63) & ~(size_t)63;
    const size_t adj_bytes    = (size_t)nrows * CAP * sizeof(int);
    const size_t cursor_bytes = ((size_t)nrows * sizeof(int) + 63) & ~(size_t)63;
    unsigned short* vw1b = (unsigned short*)d_ws;
    int*   adj  = (int*)((char*)d_ws + vw1_bytes);
    int* cursor = (int*)((char*)d_ws + vw1_bytes + adj_bytes);
    int* ovf_cnt = (int*)((char*)d_ws + vw1_bytes + adj_bytes + cursor_bytes);
    int2* ovf_list = (int2*)((char*)ovf_cnt + 64);
    const size_t fixed_bytes = vw1_bytes + adj_bytes + cursor_bytes + 64;
    long long ovf_cap = 0;
    if (ws_size > fixed_bytes) ovf_cap = (long long)((ws_size - fixed_bytes) / sizeof(int2));
    if (ovf_cap > 2LL * nedges) ovf_cap = 2LL * nedges;
    const bool csr_ok = (ws_size >= fixed_bytes) && (ovf_cap >= 4096);

    const int ngemm = (nrows + 63) / 64;

    if (csr_ok) {
        const int zblocks = (nrows + 255) / 256;
        zero_cursor_kernel<<<zblocks, 256, 0, stream>>>(cursor, nrows, ovf_cnt);

        const int npairs = (nedges + 1) / 2;
        const int nb     = (npairs + 255) / 256;
        const int ntot   = nb + ngemm;
        fused_gemm_build_kernel<<<ntot, 256, 0, stream>>>(
            verts, w0k, w0b, w1k, w1b, out, vw1b, nrows,
            edges, cursor, adj, nedges,
            ovf_cnt, ovf_list, (int)ovf_cap, nb, ntot);

        const long long ngroups = (long long)nrows * 16;
        const int vblocks = (int)((ngroups + 255) / 256);
        gather_kernel<<<vblocks, 256, 0, stream>>>(cursor, adj, vw1b, out, nrows);

        ovf_apply_kernel<<<64, 256, 0, stream>>>(ovf_cnt, ovf_list,
                                                 (int)ovf_cap, vw1b, out);
    } else {
        // gemm-only pass through the fused kernel (nb = 0 -> all gemm blocks)
        fused_gemm_build_kernel<<<ngemm, 256, 0, stream>>>(
            verts, w0k, w0b, w1k, w1b, out, vw1b, nrows,
            edges, (int*)d_ws, (int*)d_ws, 0,
            (int*)d_ws, (int2*)d_ws, 0, 0, ngemm);
        const long long ngroups = (long long)nedges * 16;
        const int blocks = (int)((ngroups + 255) / 256);
        scatter_add_kernel<<<blocks, 256, 0, stream>>>(edges, vw1b, out, nedges);
    }
}